// Round 4
// baseline (431.642 us; speedup 1.0000x reference)
//
#include <hip/hip_runtime.h>
#include <hip/hip_bf16.h>
#include <hip/hip_fp8.h>

// ContrastiveLoss (SimCLR InfoNCE): N=8192, D=1024, T=0.1
// nll[i] = -logit[i, (i+N/2)%N] + logsumexp_j(logit[i,j]), diag masked out
// logit = cos_sim / T; out = mean(nll)
//
// Identities:
//  - zn_i = z_i * sqrt(10*log2e)/||z_i||  =>  dot d = logit*log2e and
//    exp(logit-10) = 2^(d - 10*log2e) -> raw v_exp_f32.
//  - logit in [-10,10] => FIXED-offset logsumexp; masked diagonal term is
//    exactly 0, handled only in the 64 diagonal supertiles.
//  - Gram symmetric: upper-tri 128x128 supertiles (2080 of 4096); off-diag
//    tile (I,J) adds exp row-sums to rows of I, col-sums to rows of J.
//  - positive-pair logits = tile diagonals of supertiles (I, I+32).
//  - MX-scaled fp8 K=128 MFMA with all scales = 1.0 (2x bf16 rate).
//
// R16: persistent blocks + dynamic tile claiming. Evidence: R12-R15 (four
// different staging/wait schedules) all 65-69us, no pipe >23% -> cost is
// not scheduling. Accounting vs m148 (same structure, MX-fp8, 1628 TF; we
// run 1030 TF): the 1.58x gap = per-TILE overheads -- K=1024 gives only 8
// phases, so the per-tile pipeline fill (~2 phases) is ~25%, plus the LSE
// epilogue serialized per tile (~10-15%). Fix: each block claims tiles from
// a global atomic counter and chains them: staging of tile t+1 phase 0
// issues during tile t phase 7 -> ONE fill bubble per block lifetime, not
// per tile. Epilogue runs inside the stream (at next tile's phase 0, after
// its staging is issued) behind an lgkm-only s_barrier so staging loads +
// atomics stay in flight through it. Dynamic claims are work-conserving
// across CUs (no block-round quantization). R12 skeleton otherwise: 50 KB
// LDS (A dbuf + single B with reg-hoist), 3 blocks/CU, grid = 512.

#define N_ROWS 8192
#define DIM    1024
#define BM 128
#define BK 128                         // bytes (= elems) of K per phase
#define NPHASE (DIM / BK)              // 8
#define NT     (N_ROWS / BM)           // 64
#define NTILES (NT * (NT + 1) / 2)     // 2080
#define NBLOCKS 512                    // persistent blocks (2/CU, 3 fit)
#define OFFS   14.4269504088896340f    // 10 * log2e
#define ROW_SCALE 3.7982825605f        // sqrt(10 * log2e)
#define LN2    0.6931471805599453f
#define LOGIT_MAX 10.0f
#define SCALE1 0x7F7F7F7F              // e8m0 1.0 in every byte

typedef float floatx4 __attribute__((ext_vector_type(4)));
typedef int   intx4   __attribute__((ext_vector_type(4)));
typedef int   intx8   __attribute__((ext_vector_type(8)));

__device__ __forceinline__ void async_copy16(const void* g, void* lds) {
  __builtin_amdgcn_global_load_lds(
      (const __attribute__((address_space(1))) void*)g,
      (__attribute__((address_space(3))) void*)lds, 16, 0, 0);
}

__device__ __forceinline__ unsigned pack4_e4m3(float a, float b, float c, float d) {
  __hip_fp8_e4m3 qa(a), qb(b), qc(c), qd(d);
  return (unsigned)qa.__x | ((unsigned)qb.__x << 8) |
         ((unsigned)qc.__x << 16) | ((unsigned)qd.__x << 24);
}

// ---------------- Kernel 1: row normalize -> fp8 (+ zero accumulators) ----
__global__ __launch_bounds__(256) void normalize_kernel(
    const float* __restrict__ z, unsigned char* __restrict__ zn,
    float* __restrict__ sumexp, float* __restrict__ out,
    int* __restrict__ cnt) {
  const int tid = threadIdx.x, wave = tid >> 6, lane = tid & 63;
  const int row = blockIdx.x * 4 + wave;

  if (blockIdx.x < 8) ((float4*)sumexp)[blockIdx.x * 256 + tid] = float4{0, 0, 0, 0};
  if (blockIdx.x == 8 && tid == 0) out[0] = 0.0f;
  if (blockIdx.x == 8 && tid == 1) cnt[0] = 0;

  const float4* zr = (const float4*)(z + (size_t)row * DIM);
  float4 v[4];
  #pragma unroll
  for (int j = 0; j < 4; j++) v[j] = zr[lane + 64 * j];
  float ss = 0.0f;
  #pragma unroll
  for (int j = 0; j < 4; j++)
    ss += v[j].x * v[j].x + v[j].y * v[j].y + v[j].z * v[j].z + v[j].w * v[j].w;
  #pragma unroll
  for (int off = 32; off > 0; off >>= 1) ss += __shfl_xor(ss, off);
  const float scale = rsqrtf(ss) * ROW_SCALE;  // norms ~32 >> eps

  unsigned* o = (unsigned*)(zn + (size_t)row * DIM);
  #pragma unroll
  for (int j = 0; j < 4; j++)
    o[lane + 64 * j] = pack4_e4m3(v[j].x * scale, v[j].y * scale,
                                  v[j].z * scale, v[j].w * scale);
}

// decode upper-tri supertile t -> (I, J), I<=J<64; C(I) = I*(129-I)/2
__device__ __forceinline__ void decode_tile(int t, int& I, int& J) {
  int i = (int)(64.5f - sqrtf(64.5f * 64.5f - 2.0f * (float)t));
  while ((i + 1) * (129 - (i + 1)) / 2 <= t) ++i;
  while (i * (129 - i) / 2 > t) --i;
  I = i;
  J = i + (t - i * (129 - i) / 2);
}

// ---------------- Kernel 2: upper-tri MX-fp8 GEMM + partial sum-exp -------
__global__ __launch_bounds__(256, 3) void fused_gemm_lse(
    const unsigned char* __restrict__ zn, float* __restrict__ sumexp,
    float* __restrict__ pos, int* __restrict__ cnt) {
  __shared__ unsigned char sA[2][BM * BK];    // 2 x 16 KB (double buffer)
  __shared__ unsigned char sB[BM * BK];       // 16 KB (single, reg-hoisted)
  __shared__ float rowRed[2][BM];             // 1 KB
  __shared__ float colRed[2][BM];             // 1 KB
  __shared__ int sCur, sClaim;                //  (total ~50 KB)

  const int tid  = threadIdx.x;
  const int lane = tid & 63;
  const int wave = tid >> 6;
  const int quad = lane >> 4;
  const int l15  = lane & 15;
  const int waveM = wave >> 1;  // 0..1
  const int waveN = wave & 1;   // 0..1

  // per-thread staging geometry (tile-invariant).
  // chunk s: row r = s>>3, stored slot s&7 holds logical k-chunk
  // q = (s&7) ^ (r&7)  (XOR swizzle on the global-address side).
  int rOff[4], soff[4];
  #pragma unroll
  for (int i = 0; i < 4; i++) {
    const int s = i * 256 + tid;
    const int r = s >> 3;
    const int q = (s & 7) ^ (r & 7);
    rOff[i] = r * DIM + q * 16;
    soff[i] = s * 16;
  }

  // claim first two tiles
  if (tid == 0) {
    sCur   = atomicAdd(cnt, 1);
    sClaim = atomicAdd(cnt, 1);
  }
  __syncthreads();
  int cur = sCur, nxt = sClaim;
  if (cur >= NTILES) return;

  int I, J;
  decode_tile(cur, I, J);
  int rowBase = I * BM, colBase = J * BM;

  auto stageA = [&](int buf, int rb, int p) {
    const unsigned char* g = zn + (size_t)rb * DIM + p * BK;
    #pragma unroll
    for (int i = 0; i < 4; i++)
      async_copy16(g + rOff[i], (char*)sA[buf] + soff[i]);
  };
  auto stageB = [&](int cb, int p) {
    const unsigned char* g = zn + (size_t)cb * DIM + p * BK;
    #pragma unroll
    for (int i = 0; i < 4; i++)
      async_copy16(g + rOff[i], (char*)sB + soff[i]);
  };

  floatx4 acc[4][4];
  #pragma unroll
  for (int mi = 0; mi < 4; mi++)
    #pragma unroll
    for (int ni = 0; ni < 4; ni++) acc[mi][ni] = {0.f, 0.f, 0.f, 0.f};

  int pI = -1, pJ = -1;  // previous tile (acc holds its result at p==0)

  // epilogue for tile (pI,pJ); consumes acc, re-zeroes it. lgkm-only
  // barrier so in-flight staging loads are NOT drained.
  auto epilogue = [&]() {
    const int erB = pI * BM, ecB = pJ * BM;
    const bool diagBlk = (pI == pJ);

    if (pJ == pI + 32 && waveM == waveN) {  // positive-pair supertile
      #pragma unroll
      for (int mi = 0; mi < 4; mi++)
        #pragma unroll
        for (int r = 0; r < 4; r++)
          if (l15 == quad * 4 + r)
            pos[erB + waveM * 64 + mi * 16 + l15] = acc[mi][mi][r];
    }

    float rsum[4][4], csum[4];
    #pragma unroll
    for (int mi = 0; mi < 4; mi++)
      #pragma unroll
      for (int r = 0; r < 4; r++) rsum[mi][r] = 0.0f;
    #pragma unroll
    for (int ni = 0; ni < 4; ni++) csum[ni] = 0.0f;

    if (diagBlk) {
      #pragma unroll
      for (int mi = 0; mi < 4; mi++)
        #pragma unroll
        for (int ni = 0; ni < 4; ni++) {
          const bool dtile = (waveM == waveN) && (mi == ni);
          #pragma unroll
          for (int r = 0; r < 4; r++) {
            float e = exp2f(acc[mi][ni][r] - OFFS);
            if (dtile && l15 == quad * 4 + r) e = 0.0f;  // masked diagonal
            rsum[mi][r] += e;
          }
        }
    } else {
      #pragma unroll
      for (int mi = 0; mi < 4; mi++)
        #pragma unroll
        for (int ni = 0; ni < 4; ni++)
          #pragma unroll
          for (int r = 0; r < 4; r++) {
            const float e = exp2f(acc[mi][ni][r] - OFFS);
            rsum[mi][r] += e;
            csum[ni]    += e;
          }
    }

    #pragma unroll
    for (int mi = 0; mi < 4; mi++)
      #pragma unroll
      for (int r = 0; r < 4; r++) {
        float v = rsum[mi][r];
        v += __shfl_xor(v, 1);
        v += __shfl_xor(v, 2);
        v += __shfl_xor(v, 4);
        v += __shfl_xor(v, 8);
        if (l15 == 0)
          rowRed[waveN][waveM * 64 + mi * 16 + quad * 4 + r] = v;
      }
    if (!diagBlk) {
      #pragma unroll
      for (int ni = 0; ni < 4; ni++) {
        float v = csum[ni];
        v += __shfl_xor(v, 16);
        v += __shfl_xor(v, 32);
        if (quad == 0)
          colRed[waveM][waveN * 64 + ni * 16 + l15] = v;
      }
    }
    asm volatile("s_waitcnt lgkmcnt(0)" ::: "memory");
    __builtin_amdgcn_s_barrier();        // lgkm-only: vmem stays in flight
    if (tid < BM) {
      atomicAdd(&sumexp[erB + tid], rowRed[0][tid] + rowRed[1][tid]);
    } else if (!diagBlk) {
      const int c = tid - BM;
      atomicAdd(&sumexp[ecB + c], colRed[0][c] + colRed[1][c]);
    }
    #pragma unroll
    for (int mi = 0; mi < 4; mi++)
      #pragma unroll
      for (int ni = 0; ni < 4; ni++) acc[mi][ni] = {0.f, 0.f, 0.f, 0.f};
  };

  // prologue staging: tile cur, phase 0 (the ONLY cold fill per block)
  stageA(0, rowBase, 0);
  stageB(colBase, 0);

  while (true) {
    int nI = 0, nJ = 0, newNxt = NTILES;
    #pragma unroll
    for (int p = 0; p < NPHASE; ++p) {
      __syncthreads();                 // phase (cur,p) staged data ready
      if (p == 0 && tid == 0) sClaim = atomicAdd(cnt, 1);  // claim ahead

      // hoist B[p] fragments to registers (sB re-staged below)
      intx8 bb[4];
      #pragma unroll
      for (int ni = 0; ni < 4; ni++) {
        const int r = waveN * 64 + ni * 16 + l15;
        const int c0 = (quad * 2) ^ (r & 7);
        const intx4 lo = *(const intx4*)(&sB[0] + (r * 8 + c0) * 16);
        const intx4 hi = *(const intx4*)(&sB[0] + (r * 8 + (c0 ^ 1)) * 16);
        bb[ni] = __builtin_shufflevector(lo, hi, 0, 1, 2, 3, 4, 5, 6, 7);
      }
      __syncthreads();                 // all waves done with sB / sA[b^1] free

      if (p == 6) {                    // claimed id visible (>=2 barriers)
        newNxt = sClaim;
        if (nxt < NTILES) decode_tile(nxt, nI, nJ);
      }

      // stage stream position p+1 (wraps into next tile's phase 0)
      if (p < NPHASE - 1) {
        stageA((p + 1) & 1, rowBase, p + 1);
        stageB(colBase, p + 1);
      } else if (nxt < NTILES) {
        stageA(0, nI * BM, 0);
        stageB(nJ * BM, 0);
      }

      // previous tile's epilogue, overlapped with in-flight staging
      if (p == 0 && pI >= 0) epilogue();

      // A-frag reads + 16 MFMAs (phase p, buffer p&1)
      #pragma unroll
      for (int mi = 0; mi < 4; mi++) {
        const int r = waveM * 64 + mi * 16 + l15;
        const int c0 = (quad * 2) ^ (r & 7);
        const intx4 lo = *(const intx4*)(&sA[p & 1][0] + (r * 8 + c0) * 16);
        const intx4 hi = *(const intx4*)(&sA[p & 1][0] + (r * 8 + (c0 ^ 1)) * 16);
        const intx8 a = __builtin_shufflevector(lo, hi, 0, 1, 2, 3, 4, 5, 6, 7);
        #pragma unroll
        for (int ni = 0; ni < 4; ni++)
          acc[mi][ni] = __builtin_amdgcn_mfma_scale_f32_16x16x128_f8f6f4(
              a, bb[ni], acc[mi][ni],
              0 /*cbsz: A=e4m3*/, 0 /*blgp: B=e4m3*/,
              0, SCALE1,   // opsel_a, scale_a = 1.0
              0, SCALE1);  // opsel_b, scale_b = 1.0
      }
    }

    // rotate tiles
    pI = I; pJ = J;
    if (nxt >= NTILES) break;
    cur = nxt; I = nI; J = nJ;
    rowBase = I * BM; colBase = J * BM;
    nxt = newNxt;
  }

  epilogue();  // final tile
}

// ---------------- Kernel 3: mean NLL --------------------------------------
__global__ __launch_bounds__(256) void finalize_kernel(
    const float* __restrict__ sumexp, const float* __restrict__ pos,
    float* __restrict__ out) {
  const int tid = threadIdx.x;
  const int row = blockIdx.x * 256 + tid;
  // pos holds d = logit*log2e for rows [0,4096); pos[i+4096] == pos[i]
  float local = -(pos[row & (N_ROWS / 2 - 1)] * LN2) + LOGIT_MAX + logf(sumexp[row]);
  #pragma unroll
  for (int off = 32; off > 0; off >>= 1) local += __shfl_xor(local, off);
  __shared__ float red[4];
  const int wave = tid >> 6, lane = tid & 63;
  if (lane == 0) red[wave] = local;
  __syncthreads();
  if (tid == 0)
    atomicAdd(out, (red[0] + red[1] + red[2] + red[3]) * (1.0f / N_ROWS));
}

extern "C" void kernel_launch(void* const* d_in, const int* in_sizes, int n_in,
                              void* d_out, int out_size, void* d_ws, size_t ws_size,
                              hipStream_t stream) {
  const float* z = (const float*)d_in[0];
  float* out = (float*)d_out;

  char* ws = (char*)d_ws;
  unsigned char* zn = (unsigned char*)ws;                    // 8 MB fp8
  float* sumexp = (float*)(ws + (size_t)N_ROWS * DIM);       // 32 KB
  float* pos    = sumexp + N_ROWS;                           // 32 KB
  int*   cnt    = (int*)(pos + N_ROWS);                      // 4 B

  normalize_kernel<<<N_ROWS / 4, 256, 0, stream>>>(z, zn, sumexp, out, cnt);
  fused_gemm_lse<<<NBLOCKS, 256, 0, stream>>>(zn, sumexp, pos, cnt);
  finalize_kernel<<<N_ROWS / 256, 256, 0, stream>>>(sumexp, pos, out);
}

// Round 5
// 126.261 us; speedup vs baseline: 3.4187x; 3.4187x over previous
//
#include <hip/hip_runtime.h>
#include <hip/hip_bf16.h>
#include <hip/hip_fp8.h>

// ContrastiveLoss (SimCLR InfoNCE): N=8192, D=1024, T=0.1
// nll[i] = -logit[i, (i+N/2)%N] + logsumexp_j(logit[i,j]), diag masked out
// logit = cos_sim / T; out = mean(nll)
//
// Identities:
//  - zn_i = z_i * sqrt(10*log2e)/||z_i||  =>  dot d = logit*log2e and
//    exp(logit-10) = 2^(d - 10*log2e) -> raw v_exp_f32.
//  - logit in [-10,10] => FIXED-offset logsumexp; masked diagonal term is
//    exactly 0, handled only in the 64 diagonal supertiles.
//  - Gram symmetric: upper-tri 128x128 supertiles (2080 of 4096); off-diag
//    tile (I,J) adds exp row-sums to rows of I, col-sums to rows of J.
//  - positive-pair logits = tile diagonals of supertiles (I, I+32).
//  - MX-scaled fp8 K=128 MFMA with all scales = 1.0 (2x bf16 rate).
//
// R17: L2-locality tile ordering (single-variable change on the R12 code,
// which is reverted to byte-identical otherwise). Evidence: R12-R15 = four
// schedules (drain / counted-vmcnt / reg ping-pong / reg-staging) all at
// 65-69us, every pipe <23%, invariant to occupancy -> not scheduling, not
// issue, not DMA. The invariant: panel traffic 532MB at 13.2 B/cy/CU with
// zn (8MB) > per-XCD L2 (4MB); row-major tile order gives the ~96
// concurrent tiles/XCD a ~6MB B-panel working set -> B thrashes L2, every
// B staging read is a ~700cy miss; per-CU miss concurrency (MSHRs x 64B /
// latency) caps staging at ~13 B/cy regardless of schedule (Little's law).
// R16's persistent-claim attempt spilled acc to scratch (VGPR 84, WRITE
// 819MB) - disqualified, reverted. Fix here: enumerate tiles supercell-
// major -- 8x8 supercells (36 cells; diag cell = 36 tiles, off-diag = 64),
// snake within supercell rows, then the same 8-chunk XCD split. Concurrent
// window/XCD = ~1.5 cells = ~24 panels = 3MB -> fits L2; B-panels get
// 8-16x L2 reuse (vs ~1x), A-panels shared across a cell row. Predicted:
// FETCH 66->~30MB, gemm 65 -> ~45-50us if the miss-concurrency theory
// holds; neutral-with-lower-FETCH kills the memory-side theory.

#define N_ROWS 8192
#define DIM    1024
#define BM 128
#define BK 128                         // bytes (= elems) of K per phase
#define NPHASE (DIM / BK)              // 8
#define NT     (N_ROWS / BM)           // 64
#define NTILES (NT * (NT + 1) / 2)     // 2080
#define OFFS   14.4269504088896340f    // 10 * log2e
#define ROW_SCALE 3.7982825605f        // sqrt(10 * log2e)
#define LN2    0.6931471805599453f
#define LOGIT_MAX 10.0f
#define SCALE1 0x7F7F7F7F              // e8m0 1.0 in every byte

typedef float floatx4 __attribute__((ext_vector_type(4)));
typedef int   intx4   __attribute__((ext_vector_type(4)));
typedef int   intx8   __attribute__((ext_vector_type(8)));

__device__ __forceinline__ void async_copy16(const void* g, void* lds) {
  __builtin_amdgcn_global_load_lds(
      (const __attribute__((address_space(1))) void*)g,
      (__attribute__((address_space(3))) void*)lds, 16, 0, 0);
}

__device__ __forceinline__ unsigned pack4_e4m3(float a, float b, float c, float d) {
  __hip_fp8_e4m3 qa(a), qb(b), qc(c), qd(d);
  return (unsigned)qa.__x | ((unsigned)qb.__x << 8) |
         ((unsigned)qc.__x << 16) | ((unsigned)qd.__x << 24);
}

// ---------------- Kernel 1: row normalize -> fp8 (+ zero accumulators) ----
__global__ __launch_bounds__(256) void normalize_kernel(
    const float* __restrict__ z, unsigned char* __restrict__ zn,
    float* __restrict__ sumexp, float* __restrict__ out) {
  const int tid = threadIdx.x, wave = tid >> 6, lane = tid & 63;
  const int row = blockIdx.x * 4 + wave;

  if (blockIdx.x < 8) ((float4*)sumexp)[blockIdx.x * 256 + tid] = float4{0, 0, 0, 0};
  if (blockIdx.x == 8 && tid == 0) out[0] = 0.0f;

  const float4* zr = (const float4*)(z + (size_t)row * DIM);
  float4 v[4];
  #pragma unroll
  for (int j = 0; j < 4; j++) v[j] = zr[lane + 64 * j];
  float ss = 0.0f;
  #pragma unroll
  for (int j = 0; j < 4; j++)
    ss += v[j].x * v[j].x + v[j].y * v[j].y + v[j].z * v[j].z + v[j].w * v[j].w;
  #pragma unroll
  for (int off = 32; off > 0; off >>= 1) ss += __shfl_xor(ss, off);
  const float scale = rsqrtf(ss) * ROW_SCALE;  // norms ~32 >> eps

  unsigned* o = (unsigned*)(zn + (size_t)row * DIM);
  #pragma unroll
  for (int j = 0; j < 4; j++)
    o[lane + 64 * j] = pack4_e4m3(v[j].x * scale, v[j].y * scale,
                                  v[j].z * scale, v[j].w * scale);
}

// Supercell-major tile decode: 64x64 upper-tri grid partitioned into 8x8
// supercells (rows SI, cols SJ >= SI). Diag supercell = 36 tiles (upper-tri
// 8x8), off-diag = 64 (full 8x8). Cell-row SI holds 36 + (7-SI)*64 tiles;
// prefix P(SI) = 516*SI - 32*SI*SI (P(8)=2080). Within a cell-row: diag
// cell first, then off-diag cells with snake order (even SI: SJ ascending,
// odd SI: descending) so adjacent cells share B panels at row turns; all
// cells in a row share the same A panels. Within cell: row-major (i,j).
__device__ __forceinline__ void decode_tile(int g, int& I, int& J) {
  int SI = 0;
  #pragma unroll
  for (int s = 1; s < 8; ++s)
    if (516 * s - 32 * s * s <= g) SI = s;
  int rem = g - (516 * SI - 32 * SI * SI);
  int i, j, SJ;
  if (rem < 36) {                       // diagonal supercell, upper-tri 8x8
    SJ = SI;
    i = 0;
    while ((i + 1) * (17 - (i + 1)) / 2 <= rem) ++i;  // prefix(i)=i*(17-i)/2
    j = i + (rem - i * (17 - i) / 2);
  } else {                              // full off-diagonal supercell
    const int rem2 = rem - 36;
    const int cc = rem2 >> 6;           // 0 .. (6-SI)
    const int k  = rem2 & 63;
    SJ = (SI & 1) ? (7 - cc) : (SI + 1 + cc);
    i = k >> 3;
    j = k & 7;
  }
  I = SI * 8 + i;
  J = SJ * 8 + j;
}

// ---------------- Kernel 2: upper-tri MX-fp8 GEMM + partial sum-exp -------
__global__ __launch_bounds__(256, 3) void fused_gemm_lse(
    const unsigned char* __restrict__ zn, float* __restrict__ sumexp,
    float* __restrict__ pos) {
  __shared__ unsigned char sA[2][BM * BK];    // 2 x 16 KB (double buffer)
  __shared__ unsigned char sB[BM * BK];       // 16 KB (single buffer)
  __shared__ float rowRed[2][BM];             // 1 KB
  __shared__ float colRed[2][BM];             // 1 KB   (total 50 KB)

  const int tid  = threadIdx.x;
  const int lane = tid & 63;
  const int wave = tid >> 6;
  const int quad = lane >> 4;
  const int l15  = lane & 15;
  const int waveM = wave >> 1;  // 0..1
  const int waveN = wave & 1;   // 0..1

  // XCD-contiguous tile permutation (2080 = 8 * 260)
  const int t = (blockIdx.x & 7) * (NTILES / 8) + (blockIdx.x >> 3);
  int I, J;
  decode_tile(t, I, J);
  const int rowBase = I * BM, colBase = J * BM;

  // staging: 128x128B tile = 1024 16B-chunks, 4/thread/matrix.
  // chunk s: row r = s>>3, stored slot s&7 holds logical 16B k-chunk
  // q = (s&7) ^ (r&7)  (XOR swizzle, applied on the global-address side).
  const unsigned char* aP[4];
  const unsigned char* bP[4];
  int soff[4];
  #pragma unroll
  for (int i = 0; i < 4; i++) {
    const int s = i * 256 + tid;            // i*256 + wave*64 + lane
    const int r = s >> 3;                   // tile row 0..127
    const int q = (s & 7) ^ (r & 7);        // logical k-chunk 0..7
    aP[i] = zn + (size_t)(rowBase + r) * DIM + q * 16;
    bP[i] = zn + (size_t)(colBase + r) * DIM + q * 16;
    soff[i] = s * 16;                       // wave-uniform base + lane*16
  }
  auto stageA = [&](int b) {
    #pragma unroll
    for (int i = 0; i < 4; i++) {
      async_copy16(aP[i], (char*)sA[b] + soff[i]);
      aP[i] += BK;
    }
  };
  auto stageB = [&]() {
    #pragma unroll
    for (int i = 0; i < 4; i++) {
      async_copy16(bP[i], (char*)sB + soff[i]);
      bP[i] += BK;
    }
  };

  floatx4 acc[4][4];
  #pragma unroll
  for (int mi = 0; mi < 4; mi++)
    #pragma unroll
    for (int ni = 0; ni < 4; ni++) acc[mi][ni] = {0.f, 0.f, 0.f, 0.f};

  stageA(0);
  stageB();

  for (int p = 0; p < NPHASE; ++p) {
    const int b = p & 1;
    __syncthreads();                 // entry drain: A[p] (dbuf b), B[p] ready

    // hoist B[p] fragments to registers (Bbuf freed after barrier2)
    intx8 bb[4];
    #pragma unroll
    for (int ni = 0; ni < 4; ni++) {
      const int r = waveN * 64 + ni * 16 + l15;
      const int c0 = (quad * 2) ^ (r & 7);
      const intx4 lo = *(const intx4*)(&sB[0] + (r * 8 + c0) * 16);
      const intx4 hi = *(const intx4*)(&sB[0] + (r * 8 + (c0 ^ 1)) * 16);
      bb[ni] = __builtin_shufflevector(lo, hi, 0, 1, 2, 3, 4, 5, 6, 7);
    }
    __syncthreads();                 // all waves done with B[p] (lgkm-only)

    if (p + 1 < NPHASE) {            // async prefetch of phase p+1
      stageA(b ^ 1);
      stageB();
    }

    #pragma unroll
    for (int mi = 0; mi < 4; mi++) {
      const int r = waveM * 64 + mi * 16 + l15;
      const int c0 = (quad * 2) ^ (r & 7);
      const intx4 lo = *(const intx4*)(&sA[b][0] + (r * 8 + c0) * 16);
      const intx4 hi = *(const intx4*)(&sA[b][0] + (r * 8 + (c0 ^ 1)) * 16);
      const intx8 a = __builtin_shufflevector(lo, hi, 0, 1, 2, 3, 4, 5, 6, 7);
      #pragma unroll
      for (int ni = 0; ni < 4; ni++)
        acc[mi][ni] = __builtin_amdgcn_mfma_scale_f32_16x16x128_f8f6f4(
            a, bb[ni], acc[mi][ni],
            0 /*cbsz: A=e4m3*/, 0 /*blgp: B=e4m3*/,
            0, SCALE1,   // opsel_a, scale_a = 1.0
            0, SCALE1);  // opsel_b, scale_b = 1.0
    }
  }

  // ---- epilogue ----
  // C/D layout (16x16 shape family): col = lane&15, row = quad*4 + reg
  const bool diagBlk = (I == J);

  if (J == I + 32 && waveM == waveN) {  // positive-pair supertile
    #pragma unroll
    for (int mi = 0; mi < 4; mi++)
      #pragma unroll
      for (int r = 0; r < 4; r++)
        if (l15 == quad * 4 + r)
          pos[rowBase + waveM * 64 + mi * 16 + l15] = acc[mi][mi][r];
  }

  float rsum[4][4], csum[4];
  #pragma unroll
  for (int mi = 0; mi < 4; mi++)
    #pragma unroll
    for (int r = 0; r < 4; r++) rsum[mi][r] = 0.0f;
  #pragma unroll
  for (int ni = 0; ni < 4; ni++) csum[ni] = 0.0f;

  if (diagBlk) {
    #pragma unroll
    for (int mi = 0; mi < 4; mi++)
      #pragma unroll
      for (int ni = 0; ni < 4; ni++) {
        const bool dtile = (waveM == waveN) && (mi == ni);
        #pragma unroll
        for (int r = 0; r < 4; r++) {
          float e = exp2f(acc[mi][ni][r] - OFFS);
          if (dtile && l15 == quad * 4 + r) e = 0.0f;  // masked diagonal
          rsum[mi][r] += e;
        }
      }
  } else {
    #pragma unroll
    for (int mi = 0; mi < 4; mi++)
      #pragma unroll
      for (int ni = 0; ni < 4; ni++)
        #pragma unroll
        for (int r = 0; r < 4; r++) {
          const float e = exp2f(acc[mi][ni][r] - OFFS);
          rsum[mi][r] += e;
          csum[ni]    += e;
        }
  }

  #pragma unroll
  for (int mi = 0; mi < 4; mi++)
    #pragma unroll
    for (int r = 0; r < 4; r++) {
      float v = rsum[mi][r];
      v += __shfl_xor(v, 1);
      v += __shfl_xor(v, 2);
      v += __shfl_xor(v, 4);
      v += __shfl_xor(v, 8);
      if (l15 == 0)
        rowRed[waveN][waveM * 64 + mi * 16 + quad * 4 + r] = v;
    }
  if (!diagBlk) {
    #pragma unroll
    for (int ni = 0; ni < 4; ni++) {
      float v = csum[ni];
      v += __shfl_xor(v, 16);
      v += __shfl_xor(v, 32);
      if (quad == 0)
        colRed[waveM][waveN * 64 + ni * 16 + l15] = v;
    }
  }
  __syncthreads();

  if (tid < BM) {
    atomicAdd(&sumexp[rowBase + tid], rowRed[0][tid] + rowRed[1][tid]);
  } else if (!diagBlk) {
    const int c = tid - BM;
    atomicAdd(&sumexp[colBase + c], colRed[0][c] + colRed[1][c]);
  }
}

// ---------------- Kernel 3: mean NLL --------------------------------------
__global__ __launch_bounds__(256) void finalize_kernel(
    const float* __restrict__ sumexp, const float* __restrict__ pos,
    float* __restrict__ out) {
  const int tid = threadIdx.x;
  const int row = blockIdx.x * 256 + tid;
  // pos holds d = logit*log2e for rows [0,4096); pos[i+4096] == pos[i]
  float local = -(pos[row & (N_ROWS / 2 - 1)] * LN2) + LOGIT_MAX + logf(sumexp[row]);
  #pragma unroll
  for (int off = 32; off > 0; off >>= 1) local += __shfl_xor(local, off);
  __shared__ float red[4];
  const int wave = tid >> 6, lane = tid & 63;
  if (lane == 0) red[wave] = local;
  __syncthreads();
  if (tid == 0)
    atomicAdd(out, (red[0] + red[1] + red[2] + red[3]) * (1.0f / N_ROWS));
}

extern "C" void kernel_launch(void* const* d_in, const int* in_sizes, int n_in,
                              void* d_out, int out_size, void* d_ws, size_t ws_size,
                              hipStream_t stream) {
  const float* z = (const float*)d_in[0];
  float* out = (float*)d_out;

  char* ws = (char*)d_ws;
  unsigned char* zn = (unsigned char*)ws;                    // 8 MB fp8
  float* sumexp = (float*)(ws + (size_t)N_ROWS * DIM);       // 32 KB
  float* pos    = sumexp + N_ROWS;                           // 16 KB

  normalize_kernel<<<N_ROWS / 4, 256, 0, stream>>>(z, zn, sumexp, out);
  fused_gemm_lse<<<NTILES, 256, 0, stream>>>(zn, sumexp, pos);
  finalize_kernel<<<N_ROWS / 256, 256, 0, stream>>>(sumexp, pos, out);
}